// Round 11
// baseline (356.305 us; speedup 1.0000x reference)
//
#include <hip/hip_runtime.h>
#include <hip/hip_cooperative_groups.h>
#include <cmath>

namespace cg = cooperative_groups;

#define BB  1024
#define TT  128
#define HH1 512
#define HH2 256
#define CC  18

// d_ws layout (byte offsets)
#define WS_DIG   0ull             // W2 digits: 8x4x16x2x32x16 i8 = 512 KB
#define WS_W3D   524288ull        // W3 digits LDS image: 32 KB
#define WS_MASK  557056ull        // s1 masks[row][chunk4][word8][t32] ull = 8 MB
#define WS_MASK2 8945664ull       // s2 masks[row][t][stripe8] u32 = 4 MB

typedef int  v4i  __attribute__((ext_vector_type(4)));
typedef int  v16i __attribute__((ext_vector_type(16)));
typedef unsigned long long ull;

__device__ __forceinline__ v4i expand_bits(unsigned bits) {
  v4i a;
  a.x = (int)((( bits        & 15u) * 0x204081u) & 0x01010101u);
  a.y = (int)((((bits >>  4) & 15u) * 0x204081u) & 0x01010101u);
  a.z = (int)((((bits >>  8) & 15u) * 0x204081u) & 0x01010101u);
  a.w = (int)((((bits >> 12) & 15u) * 0x204081u) & 0x01010101u);
  return a;
}

__device__ __forceinline__ signed char dig_of(float w, int d) {
  long long ll = llrint((double)w * 4294967296.0);
  int v = (int)ll;
  signed char d0 = (signed char)(v & 255); v = (v - d0) >> 8;
  signed char d1 = (signed char)(v & 255); v = (v - d1) >> 8;
  signed char d2 = (signed char)(v & 255); v = (v - d2) >> 8;
  signed char d3 = (signed char)v;
  return (d == 0) ? d0 : (d == 1) ? d1 : (d == 2) ? d2 : d3;
}

// ---- ONE cooperative kernel: prep (W2/W3 digits + s1) -> gemmscan -> l3v3.
// 256 blocks x 512 thr, 80 KB LDS -> 1 block/CU, trivially co-resident.
// All phase numerics are verbatim from the R10 kernels (bit-exact); only the
// kernel boundaries (3 dispatch gaps, ~10 us each) are removed. grid.sync()
// + __threadfence() provides cross-XCD visibility for dig/masks/masks2
// (per-XCD L2s are not coherent; the fence+device-scope barrier is the
// device-scope release/acquire G16 requires).
__global__ __launch_bounds__(512, 2) void mega(
    const float* __restrict__ x,  const float* __restrict__ W1,
    const float* __restrict__ b1, const float* __restrict__ W2,
    const float* __restrict__ b2, const float* __restrict__ W3,
    const float* __restrict__ b3, signed char* __restrict__ dig,
    signed char* __restrict__ w3dig, ull* __restrict__ masks,
    unsigned* __restrict__ masks2, float* __restrict__ out)
{
  __shared__ __align__(16) signed char Bl[65536];
  __shared__ __align__(16) ull mbuf[16][128];      // 16 KB (xrow scratch in ph0)

  cg::grid_group grid = cg::this_grid();
  const int bid = blockIdx.x;                      // 0..255
  const int tid = threadIdx.x, lane = tid & 63, wv = tid >> 6;
  const int half = lane >> 5, l31 = lane & 31;

  // ================= phase 0a: W2 + W3 digit planes =================
  {
    const int g = bid * 512 + tid;                 // [0, 131072)
#pragma unroll
    for (int p = 0; p < 4; ++p) {
      int i = g + p * 131072;                      // [0, 524288)
      int j = i & 15, n = (i >> 4) & 31, h = (i >> 9) & 1;
      int s = (i >> 10) & 15, d = (i >> 14) & 3, st = i >> 16;
      dig[i] = dig_of(W2[(st * 32 + n) * HH1 + (s * 32 + h * 16 + j)], d);
    }
    if (g < 32768) {
      int i = g;
      int j = i & 15, col = (i >> 4) & 31, h = (i >> 9) & 1;
      int c8 = (i >> 10) & 7, d = (i >> 13) & 3;
      float w = (col < CC) ? W3[col * HH2 + (c8 * 32 + h * 16 + j)] : 0.0f;
      w3dig[i] = dig_of(w, d);
    }
  }

  // ================= phase 0b: layer-1 scan (2 passes x 2 rows/block) ======
  {
    float* xr = (float*)mbuf;                      // 2 x 128 floats
    const int grp = tid >> 8, t256 = tid & 255;    // row-group, thread-in-group
    const int wv4 = t256 >> 6;                     // word index (as standalone)
    const float w1a = W1[t256], w1b = W1[t256 + 256];
    const float b1a = b1[t256], b1b = b1[t256 + 256];
#pragma unroll
    for (int p = 0; p < 2; ++p) {
      const int row = p * 512 + bid * 2 + grp;
      if (t256 < TT) xr[grp * TT + t256] = x[row * TT + t256];
      __syncthreads();
      float v1a = 0.f, v1b = 0.f;
      ull* mp = masks + (size_t)row * 1024;
      for (int t = 0; t < TT; ++t) {
        float xt = xr[grp * TT + t];
        float iA = __fadd_rn(__fmul_rn(xt, w1a), b1a);
        v1a = __fadd_rn(v1a, iA);
        bool sA = (v1a >= 1.0f);  v1a = sA ? (v1a - 1.0f) : v1a;
        float iB = __fadd_rn(__fmul_rn(xt, w1b), b1b);
        v1b = __fadd_rn(v1b, iB);
        bool sB = (v1b >= 1.0f);  v1b = sB ? (v1b - 1.0f) : v1b;
        ull mA = __ballot(sA);
        ull mB = __ballot(sB);
        if (lane == 0) {
          ull* q = mp + (size_t)(t >> 5) * 256 + (t & 31);
          q[(size_t)wv4 * 32]       = mA;          // word wv4   : h1 [64wv4,+64)
          q[(size_t)(4 + wv4) * 32] = mB;          // word 4+wv4 : h1 [256+64wv4,+64)
        }
      }
      __syncthreads();                             // xr reuse next pass
    }
  }

  __threadfence();
  grid.sync();                                     // dig + masks visible grid-wide

  // ================= phase 1: gemmscan (R10 verbatim, 65.5 us) =============
  {
    const int rowgrp = bid & 31, stripe = bid >> 5;
    {
      const uint4* src = (const uint4*)(dig + (size_t)stripe * 65536);
      uint4* dst = (uint4*)Bl;
#pragma unroll
      for (int i = 0; i < 8; ++i) dst[tid + 512 * i] = src[tid + 512 * i];
    }

    const signed char* bbase = Bl + half * 512 + l31 * 16;
    const float b2r = b2[stripe * 32 + l31];
    const unsigned hsh = half * 16;
    const int tp1 = (l31 & 3) + ((l31 >> 3) << 2) + ((l31 & 4) ? 16 : 0);
    const int tp2 = tp1 ^ 16;

    __syncthreads();                               // Bl ready

    if (wv & 4) {                                  // de-phase stagger
      __builtin_amdgcn_s_sleep(15);
      __builtin_amdgcn_s_sleep(15);
    }

    for (int tau = 0; tau < 2; ++tau) {
      const int pr = wv + 8 * tau;
      const int r1 = rowgrp * 32 + 2 * pr;
      const ull* mb1 = masks + (size_t)r1 * 1024;
      const ull* mb2 = mb1 + 1024;
      float v2 = 0.f;

      ull wP[8], wQ[8], wPn[8], wQn[8];
#pragma unroll
      for (int k = 0; k < 8; ++k) {
        wP[k] = mb1[k * 32 + tp1];
        wQ[k] = mb2[k * 32 + tp2];
      }

#pragma unroll
      for (int c = 0; c < 4; ++c) {
        if (c < 3) {
#pragma unroll
          for (int k = 0; k < 8; ++k) {
            wPn[k] = mb1[(c + 1) * 256 + k * 32 + tp1];
            wQn[k] = mb2[(c + 1) * 256 + k * 32 + tp2];
          }
        }

        v16i aP[4], aQ[4];
#pragma unroll
        for (int d = 0; d < 4; ++d) {
          aP[d] = (v16i){0,0,0,0,0,0,0,0,0,0,0,0,0,0,0,0};
          aQ[d] = (v16i){0,0,0,0,0,0,0,0,0,0,0,0,0,0,0,0};
        }
        __builtin_amdgcn_s_setprio(1);
#pragma unroll
        for (int s = 0; s < 16; ++s) {
          v4i q0 = *(const v4i*)(bbase + (0 * 16 + s) * 1024);
          v4i q1 = *(const v4i*)(bbase + (1 * 16 + s) * 1024);
          v4i q2 = *(const v4i*)(bbase + (2 * 16 + s) * 1024);
          v4i q3 = *(const v4i*)(bbase + (3 * 16 + s) * 1024);
          unsigned shift = ((s & 1) << 5) + hsh;
          v4i eP = expand_bits((unsigned)(wP[s >> 1] >> shift) & 0xFFFFu);
          v4i eQ = expand_bits((unsigned)(wQ[s >> 1] >> shift) & 0xFFFFu);
          aP[0] = __builtin_amdgcn_mfma_i32_32x32x32_i8(eP, q0, aP[0], 0, 0, 0);
          aQ[0] = __builtin_amdgcn_mfma_i32_32x32x32_i8(eQ, q0, aQ[0], 0, 0, 0);
          aP[1] = __builtin_amdgcn_mfma_i32_32x32x32_i8(eP, q1, aP[1], 0, 0, 0);
          aQ[1] = __builtin_amdgcn_mfma_i32_32x32x32_i8(eQ, q1, aQ[1], 0, 0, 0);
          aP[2] = __builtin_amdgcn_mfma_i32_32x32x32_i8(eP, q2, aP[2], 0, 0, 0);
          aQ[2] = __builtin_amdgcn_mfma_i32_32x32x32_i8(eQ, q2, aQ[2], 0, 0, 0);
          aP[3] = __builtin_amdgcn_mfma_i32_32x32x32_i8(eP, q3, aP[3], 0, 0, 0);
          aQ[3] = __builtin_amdgcn_mfma_i32_32x32x32_i8(eQ, q3, aQ[3], 0, 0, 0);
        }
        __builtin_amdgcn_s_setprio(0);

        float dP[16], dQ[16];
#pragma unroll
        for (int r = 0; r < 16; ++r) {
          int sloP = aP[0][r] + (aP[1][r] << 8);
          int shiP = aP[2][r] + (aP[3][r] << 8);
          double ssP = fma((double)shiP, 65536.0, (double)sloP);  // exact
          dP[r] = (float)(ssP * 0x1p-32);                         // one rounding
          int sloQ = aQ[0][r] + (aQ[1][r] << 8);
          int shiQ = aQ[2][r] + (aQ[3][r] << 8);
          double ssQ = fma((double)shiQ, 65536.0, (double)sloQ);
          dQ[r] = (float)(ssQ * 0x1p-32);
        }

        const int tb = c * 32;
#pragma unroll
        for (int r = 0; r < 16; ++r) {
          float val = half ? dQ[r] : dP[r];
          float i2 = __fadd_rn(val, b2r);
          v2 = __fadd_rn(v2, i2);
          bool s2 = (v2 >= 1.0f);  v2 = s2 ? (v2 - 1.0f) : v2;
          ull m = __ballot(s2);
          if (lane == 0) mbuf[pr][tb + r] = m;
        }
        v2 = __shfl_xor(v2, 32);
#pragma unroll
        for (int r = 0; r < 16; ++r) {
          float val = half ? dP[r] : dQ[r];
          float i2 = __fadd_rn(val, b2r);
          v2 = __fadd_rn(v2, i2);
          bool s2 = (v2 >= 1.0f);  v2 = s2 ? (v2 - 1.0f) : v2;
          ull m = __ballot(s2);
          if (lane == 0) mbuf[pr][tb + 16 + r] = (m >> 32) | (m << 32);
        }
        v2 = __shfl_xor(v2, 32);

        if (c < 3) {
#pragma unroll
          for (int k = 0; k < 8; ++k) { wP[k] = wPn[k]; wQ[k] = wQn[k]; }
        }
      }
    }

    // batch flush: mbuf -> masks2[row][t][stripe8]
    __syncthreads();
    {
      const ull* mb = &mbuf[0][0];
      unsigned* base = masks2 + (size_t)rowgrp * 32 * 1024 + stripe;
#pragma unroll
      for (int i = 0; i < 4; ++i) {
        int e = i * 512 + tid;                     // [0, 2048)
        int p = e >> 7, t = e & 127;
        ull m = mb[e];
        unsigned* q = base + (size_t)(2 * p) * 1024 + t * 8;
        q[0]    = (unsigned)m;
        q[1024] = (unsigned)(m >> 32);
      }
    }
  }

  __threadfence();
  grid.sync();                                     // masks2 visible grid-wide

  // ================= phase 2: l3v3 (R10 verbatim; waves 0-3 active) ========
  {
    {
      const uint4* src = (const uint4*)w3dig;
      uint4* dst = (uint4*)Bl;
#pragma unroll
      for (int i = 0; i < 4; ++i) dst[tid + 512 * i] = src[tid + 512 * i];
    }
    __syncthreads();                               // Bl (32 KB) ready

    if (wv < 4) {
      const int row = bid * 4 + wv;
      const unsigned* mrow = masks2 + (size_t)row * (TT * 8);
      const signed char* bbase = Bl + half * 512 + l31 * 16;
      const float b3r = b3[l31 < CC ? l31 : 0];
      const unsigned hsh = half * 16;
      const int tp1 = (l31 & 3) + ((l31 >> 3) << 2) + ((l31 & 4) ? 16 : 0);

      float v3 = 0.f, ac = 0.f;

      for (int c = 0; c < 4; ++c) {
        unsigned w8[8];
        {
          const unsigned* mp = mrow + (size_t)(c * 32 + tp1) * 8;
          *(uint4*)&w8[0] = *(const uint4*)mp;
          *(uint4*)&w8[4] = *(const uint4*)(mp + 4);
        }

        v16i acc[4];
#pragma unroll
        for (int d = 0; d < 4; ++d)
          acc[d] = (v16i){0,0,0,0,0,0,0,0,0,0,0,0,0,0,0,0};

#pragma unroll
        for (int c8 = 0; c8 < 8; ++c8) {
          v4i e = expand_bits((w8[c8] >> hsh) & 0xFFFFu);
#pragma unroll
          for (int d = 0; d < 4; ++d) {
            v4i b = *(const v4i*)(bbase + (d * 8 + c8) * 1024);
            acc[d] = __builtin_amdgcn_mfma_i32_32x32x32_i8(e, b, acc[d], 0, 0, 0);
          }
        }

        float dv[16];
#pragma unroll
        for (int r = 0; r < 16; ++r) {
          int slo = acc[0][r] + (acc[1][r] << 8);
          int shi = acc[2][r] + (acc[3][r] << 8);
          double ss = fma((double)shi, 65536.0, (double)slo);
          dv[r] = (float)(ss * 0x1p-32);
        }

#pragma unroll
        for (int r = 0; r < 16; ++r) {
          float i3 = __fadd_rn(dv[r], b3r);
          float u  = __fadd_rn(v3, i3);
          bool s3  = (u >= 1.0f);
          float uv = s3 ? (u - 1.0f) : u;
          float av = __fadd_rn(ac, s3 ? 1.0f : 0.0f);
          if (!half) { v3 = uv; ac = av; }
        }
        v3 = __shfl_xor(v3, 32); ac = __shfl_xor(ac, 32);
#pragma unroll
        for (int r = 0; r < 16; ++r) {
          float i3 = __fadd_rn(dv[r], b3r);
          float u  = __fadd_rn(v3, i3);
          bool s3  = (u >= 1.0f);
          float uv = s3 ? (u - 1.0f) : u;
          float av = __fadd_rn(ac, s3 ? 1.0f : 0.0f);
          if (half) { v3 = uv; ac = av; }
        }
        v3 = __shfl_xor(v3, 32); ac = __shfl_xor(ac, 32);
      }

      if (!half && l31 < CC)
        out[row * CC + l31] = ac * (1.0f / TT);
    }
  }
}

extern "C" void kernel_launch(void* const* d_in, const int* in_sizes, int n_in,
                              void* d_out, int out_size, void* d_ws, size_t ws_size,
                              hipStream_t stream)
{
  (void)in_sizes; (void)n_in; (void)out_size; (void)ws_size;
  const float* x  = (const float*)d_in[0];
  const float* W1 = (const float*)d_in[1];
  const float* b1 = (const float*)d_in[2];
  const float* W2 = (const float*)d_in[3];
  const float* b2 = (const float*)d_in[4];
  const float* W3 = (const float*)d_in[5];
  const float* b3 = (const float*)d_in[6];
  // d_in[7] = repeat (structurally 1 for this problem shape)
  float* out = (float*)d_out;
  char*  ws  = (char*)d_ws;

  signed char* dig    = (signed char*)(ws + WS_DIG);
  signed char* w3dig  = (signed char*)(ws + WS_W3D);
  ull*         masks  = (ull*)(ws + WS_MASK);
  unsigned*    masks2 = (unsigned*)(ws + WS_MASK2);

  void* args[] = { (void*)&x, (void*)&W1, (void*)&b1, (void*)&W2, (void*)&b2,
                   (void*)&W3, (void*)&b3, (void*)&dig, (void*)&w3dig,
                   (void*)&masks, (void*)&masks2, (void*)&out };
  hipLaunchCooperativeKernel((const void*)mega, dim3(256), dim3(512),
                             args, 0, stream);
}

// Round 12
// 171.211 us; speedup vs baseline: 2.0811x; 2.0811x over previous
//
#include <hip/hip_runtime.h>
#include <cmath>

#define BB  1024
#define TT  128
#define HH1 512
#define HH2 256
#define CC  18

// d_ws layout (byte offsets)
#define WS_DIG   0ull             // W2 digits: 8x4x16x2x32x16 i8 = 512 KB
#define WS_W3D   524288ull        // W3 digits LDS image: 32 KB
#define WS_MASK  557056ull        // s1 masks[row][chunk4][word8][t32] ull = 8 MB
#define WS_MASK2 8945664ull       // s2 masks[row][t][stripe8] u32 = 4 MB

typedef int  v4i  __attribute__((ext_vector_type(4)));
typedef int  v16i __attribute__((ext_vector_type(16)));
typedef unsigned long long ull;

__device__ __forceinline__ v4i expand_bits(unsigned bits) {
  v4i a;
  a.x = (int)((( bits        & 15u) * 0x204081u) & 0x01010101u);
  a.y = (int)((((bits >>  4) & 15u) * 0x204081u) & 0x01010101u);
  a.z = (int)((((bits >>  8) & 15u) * 0x204081u) & 0x01010101u);
  a.w = (int)((((bits >> 12) & 15u) * 0x204081u) & 0x01010101u);
  return a;
}

// ---- merged weight prep: W2 digits (bid<2048) | W3 digits (bid>=2048).
__global__ __launch_bounds__(256) void prep_weights(const float* __restrict__ W2,
    const float* __restrict__ W3, signed char* __restrict__ dig,
    signed char* __restrict__ w3dig)
{
  const int bid = blockIdx.x, tid = threadIdx.x;
  if (bid < 2048) {
    int i = bid * 256 + tid;                      // [0, 524288)
    int j = i & 15, n = (i >> 4) & 31, h = (i >> 9) & 1;
    int s = (i >> 10) & 15, d = (i >> 14) & 3, st = i >> 16;
    int h1 = s * 32 + h * 16 + j;
    int h2 = st * 32 + n;
    float w = W2[h2 * HH1 + h1];
    long long ll = llrint((double)w * 4294967296.0);
    int v = (int)ll;
    signed char d0 = (signed char)(v & 255); v = (v - d0) >> 8;
    signed char d1 = (signed char)(v & 255); v = (v - d1) >> 8;
    signed char d2 = (signed char)(v & 255); v = (v - d2) >> 8;
    signed char d3 = (signed char)v;
    dig[i] = (d == 0) ? d0 : (d == 1) ? d1 : (d == 2) ? d2 : d3;
  } else {
    int i = (bid - 2048) * 256 + tid;             // [0, 32768)
    int j = i & 15, col = (i >> 4) & 31, h = (i >> 9) & 1;
    int c8 = (i >> 10) & 7, d = (i >> 13) & 3;
    int h2 = c8 * 32 + h * 16 + j;
    float w = (col < CC) ? W3[col * HH2 + h2] : 0.0f;
    long long ll = llrint((double)w * 4294967296.0);
    int v = (int)ll;
    signed char d0 = (signed char)(v & 255); v = (v - d0) >> 8;
    signed char d1 = (signed char)(v & 255); v = (v - d1) >> 8;
    signed char d2 = (signed char)(v & 255); v = (v - d2) >> 8;
    signed char d3 = (signed char)v;
    w3dig[i] = (d == 0) ? d0 : (d == 1) ? d1 : (d == 2) ? d2 : d3;
  }
}

// ---- phase A: bit-exact layer-1 spike masks for all (row,t). One block/row.
// masks layout: [row][chunk(4)][word(8)][t32]
__global__ __launch_bounds__(256) void phase_s1(const float* __restrict__ x,
    const float* __restrict__ W1, const float* __restrict__ b1,
    ull* __restrict__ masks)
{
  __shared__ float xrow[TT];
  int row = blockIdx.x, tid = threadIdx.x, wv = tid >> 6, lane = tid & 63;
  for (int i = tid; i < TT; i += 256) xrow[i] = x[row * TT + i];
  const float w1a = W1[tid], w1b = W1[tid + 256];
  const float b1a = b1[tid], b1b = b1[tid + 256];
  float v1a = 0.f, v1b = 0.f;
  __syncthreads();
  for (int t = 0; t < TT; ++t) {
    float xt = xrow[t];
    float iA = __fadd_rn(__fmul_rn(xt, w1a), b1a);
    v1a = __fadd_rn(v1a, iA);
    bool sA = (v1a >= 1.0f);  v1a = sA ? (v1a - 1.0f) : v1a;
    float iB = __fadd_rn(__fmul_rn(xt, w1b), b1b);
    v1b = __fadd_rn(v1b, iB);
    bool sB = (v1b >= 1.0f);  v1b = sB ? (v1b - 1.0f) : v1b;
    ull mA = __ballot(sA);
    ull mB = __ballot(sB);
    if (lane == 0) {
      ull* p = masks + (size_t)row * 1024 + (size_t)(t >> 5) * 256 + (t & 31);
      p[(size_t)wv * 32]       = mA;              // word wv    : h1 [64wv, +64)
      p[(size_t)(4 + wv) * 32] = mB;              // word 4+wv  : h1 [256+64wv, +64)
    }
  }
}

// ---- fused layer 2, t-as-M-dimension (R10, verified 65.5 us / MfmaUtil 44-46).
// Scan ballots stored to LDS mbuf (8 B, cheap in the serial scan chain); a
// one-time end-of-kernel flush writes masks2 in l3v3's preferred
// [row][t][stripe8] layout outside the pipelined region.
// LDS = 64 KB Bl + 16 KB mbuf = 80 KB. P/Q pairing load-bearing.
__global__ __launch_bounds__(512, 2) void phase_gemmscan(
    const signed char* __restrict__ Bd, const ull* __restrict__ masks,
    const float* __restrict__ b2, unsigned* __restrict__ masks2)
{
  __shared__ __align__(16) signed char Bl[65536];
  __shared__ __align__(16) ull mbuf[16][128];      // [pair][t] = 16 KB

  const int bid = blockIdx.x;
  const int rowgrp = bid & 31, stripe = bid >> 5; // same-rowgrp -> same XCD
  const int tid = threadIdx.x, lane = tid & 63, wv = tid >> 6;
  const int half = lane >> 5, l31 = lane & 31;

  {
    const uint4* src = (const uint4*)(Bd + (size_t)stripe * 65536);
    uint4* dst = (uint4*)Bl;
#pragma unroll
    for (int i = 0; i < 8; ++i) dst[tid + 512 * i] = src[tid + 512 * i];
  }

  const signed char* bbase = Bl + half * 512 + l31 * 16;
  const float b2r = b2[stripe * 32 + l31];
  const unsigned hsh = half * 16;

  // A-row i = l31 -> t_local. tile1: lo-half regs get t 0..15 in order.
  const int tp1 = (l31 & 3) + ((l31 >> 3) << 2) + ((l31 & 4) ? 16 : 0);
  const int tp2 = tp1 ^ 16;                       // tile2: inverted halves

  __syncthreads();                                // Bl ready

  // de-phase stagger: waves 4-7 share SIMDs with waves 0-3.
  if (wv & 4) {
    __builtin_amdgcn_s_sleep(15);
    __builtin_amdgcn_s_sleep(15);
  }

  for (int tau = 0; tau < 2; ++tau) {
    const int pr = wv + 8 * tau;                  // pair 0..15
    const int r1 = rowgrp * 32 + 2 * pr;
    const ull* mb1 = masks + (size_t)r1 * 1024;
    const ull* mb2 = mb1 + 1024;                  // row r1+1
    float v2 = 0.f;                               // lo: r1 state, hi: r2 state

    ull wP[8], wQ[8], wPn[8], wQn[8];
#pragma unroll
    for (int k = 0; k < 8; ++k) {
      wP[k] = mb1[k * 32 + tp1];
      wQ[k] = mb2[k * 32 + tp2];
    }

#pragma unroll
    for (int c = 0; c < 4; ++c) {
      if (c < 3) {                                // prefetch next chunk's masks
#pragma unroll
        for (int k = 0; k < 8; ++k) {
          wPn[k] = mb1[(c + 1) * 256 + k * 32 + tp1];
          wQn[k] = mb2[(c + 1) * 256 + k * 32 + tp2];
        }
      }

      v16i aP[4], aQ[4];
#pragma unroll
      for (int d = 0; d < 4; ++d) {
        aP[d] = (v16i){0,0,0,0,0,0,0,0,0,0,0,0,0,0,0,0};
        aQ[d] = (v16i){0,0,0,0,0,0,0,0,0,0,0,0,0,0,0,0};
      }
      __builtin_amdgcn_s_setprio(1);
#pragma unroll
      for (int s = 0; s < 16; ++s) {
        v4i q0 = *(const v4i*)(bbase + (0 * 16 + s) * 1024);
        v4i q1 = *(const v4i*)(bbase + (1 * 16 + s) * 1024);
        v4i q2 = *(const v4i*)(bbase + (2 * 16 + s) * 1024);
        v4i q3 = *(const v4i*)(bbase + (3 * 16 + s) * 1024);
        unsigned shift = ((s & 1) << 5) + hsh;
        v4i eP = expand_bits((unsigned)(wP[s >> 1] >> shift) & 0xFFFFu);
        v4i eQ = expand_bits((unsigned)(wQ[s >> 1] >> shift) & 0xFFFFu);
        aP[0] = __builtin_amdgcn_mfma_i32_32x32x32_i8(eP, q0, aP[0], 0, 0, 0);
        aQ[0] = __builtin_amdgcn_mfma_i32_32x32x32_i8(eQ, q0, aQ[0], 0, 0, 0);
        aP[1] = __builtin_amdgcn_mfma_i32_32x32x32_i8(eP, q1, aP[1], 0, 0, 0);
        aQ[1] = __builtin_amdgcn_mfma_i32_32x32x32_i8(eQ, q1, aQ[1], 0, 0, 0);
        aP[2] = __builtin_amdgcn_mfma_i32_32x32x32_i8(eP, q2, aP[2], 0, 0, 0);
        aQ[2] = __builtin_amdgcn_mfma_i32_32x32x32_i8(eQ, q2, aQ[2], 0, 0, 0);
        aP[3] = __builtin_amdgcn_mfma_i32_32x32x32_i8(eP, q3, aP[3], 0, 0, 0);
        aQ[3] = __builtin_amdgcn_mfma_i32_32x32x32_i8(eQ, q3, aQ[3], 0, 0, 0);
      }
      __builtin_amdgcn_s_setprio(0);

      // exact digit fold -> one f32 rounding (bit-identical).
      // dP[r]: tile1 value at t_local = r + 16*half; dQ[r]: r + 16*(1-half).
      float dP[16], dQ[16];
#pragma unroll
      for (int r = 0; r < 16; ++r) {
        int sloP = aP[0][r] + (aP[1][r] << 8);
        int shiP = aP[2][r] + (aP[3][r] << 8);
        double ssP = fma((double)shiP, 65536.0, (double)sloP);  // exact
        dP[r] = (float)(ssP * 0x1p-32);                         // one rounding
        int sloQ = aQ[0][r] + (aQ[1][r] << 8);
        int shiQ = aQ[2][r] + (aQ[3][r] << 8);
        double ssQ = fma((double)shiQ, 65536.0, (double)sloQ);
        dQ[r] = (float)(ssQ * 0x1p-32);
      }

      // ---- in-register v2 scan of 32 t (exact order t = tb..tb+31)
      const int tb = c * 32;
      // phase 1: lo lanes scan r1 (dP), hi lanes scan r2 (dQ); t = tb + r
#pragma unroll
      for (int r = 0; r < 16; ++r) {
        float val = half ? dQ[r] : dP[r];
        float i2 = __fadd_rn(val, b2r);
        v2 = __fadd_rn(v2, i2);
        bool s2 = (v2 >= 1.0f);  v2 = s2 ? (v2 - 1.0f) : v2;
        ull m = __ballot(s2);                     // lo32: r1 word, hi32: r2
        if (lane == 0) mbuf[pr][tb + r] = m;
      }
      v2 = __shfl_xor(v2, 32);                    // exchange row states
      // phase 2: lo lanes scan r2 (dQ), hi lanes scan r1 (dP); t = tb+16+r
#pragma unroll
      for (int r = 0; r < 16; ++r) {
        float val = half ? dP[r] : dQ[r];
        float i2 = __fadd_rn(val, b2r);
        v2 = __fadd_rn(v2, i2);
        bool s2 = (v2 >= 1.0f);  v2 = s2 ? (v2 - 1.0f) : v2;
        ull m = __ballot(s2);                     // lo32: r2 word, hi32: r1
        if (lane == 0) mbuf[pr][tb + 16 + r] = (m >> 32) | (m << 32);
      }
      v2 = __shfl_xor(v2, 32);                    // restore arrangement

      if (c < 3) {
#pragma unroll
        for (int k = 0; k < 8; ++k) { wP[k] = wPn[k]; wQ[k] = wQn[k]; }
      }
    }
  }

  // ---- batch flush: mbuf -> masks2[row][t][stripe8] (fire-and-forget)
  __syncthreads();
  {
    const ull* mb = &mbuf[0][0];
    unsigned* base = masks2 + (size_t)rowgrp * 32 * 1024 + stripe;
#pragma unroll
    for (int i = 0; i < 4; ++i) {
      int e = i * 512 + tid;                      // [0, 2048)
      int p = e >> 7, t = e & 127;                // pair, timestep
      ull m = mb[e];
      unsigned* q = base + (size_t)(2 * p) * 1024 + t * 8;
      q[0]    = (unsigned)m;                      // row rowgrp*32+2p
      q[1024] = (unsigned)(m >> 32);              // row rowgrp*32+2p+1
    }
  }
}

// ---- fused layer 3 + v3 scan (R10): t-as-M, in-register v3, no D3 buffer.
// Block = 256 thr (4 waves); wave owns ONE batch row (row = bid*4+wv), all
// 128 t. masks2 is [row][t][stripe8]: each lane reads its 8 K-words as two
// dwordx4 (32 B contiguous); a wave covers a 1 KB contiguous span per chunk.
__global__ __launch_bounds__(256) void phase_l3v3(const signed char* __restrict__ W3d,
    const unsigned* __restrict__ masks2, const float* __restrict__ b3,
    float* __restrict__ out)
{
  __shared__ __align__(16) signed char Bl[32768];
  const int bid = blockIdx.x;
  const int tid = threadIdx.x, lane = tid & 63, wv = tid >> 6;
  const int half = lane >> 5, l31 = lane & 31;

  {
    const uint4* src = (const uint4*)W3d;
    uint4* dst = (uint4*)Bl;
#pragma unroll
    for (int i = 0; i < 8; ++i) dst[tid + 256 * i] = src[tid + 256 * i];
  }

  const int row = bid * 4 + wv;
  const unsigned* mrow = masks2 + (size_t)row * (TT * 8);
  const signed char* bbase = Bl + half * 512 + l31 * 16;
  const float b3r = b3[l31 < CC ? l31 : 0];
  const unsigned hsh = half * 16;
  // A-row l31 -> t_local (same permutation as gemmscan; fold reg r = tb+r+16*half)
  const int tp1 = (l31 & 3) + ((l31 >> 3) << 2) + ((l31 & 4) ? 16 : 0);

  __syncthreads();

  float v3 = 0.f, ac = 0.f;                       // canonical state in lo lanes

  for (int c = 0; c < 4; ++c) {
    unsigned w8[8];
    {
      const unsigned* mp = mrow + (size_t)(c * 32 + tp1) * 8;
      *(uint4*)&w8[0] = *(const uint4*)mp;
      *(uint4*)&w8[4] = *(const uint4*)(mp + 4);
    }

    v16i acc[4];
#pragma unroll
    for (int d = 0; d < 4; ++d)
      acc[d] = (v16i){0,0,0,0,0,0,0,0,0,0,0,0,0,0,0,0};

#pragma unroll
    for (int c8 = 0; c8 < 8; ++c8) {
      v4i e = expand_bits((w8[c8] >> hsh) & 0xFFFFu);
#pragma unroll
      for (int d = 0; d < 4; ++d) {
        v4i b = *(const v4i*)(bbase + (d * 8 + c8) * 1024);
        acc[d] = __builtin_amdgcn_mfma_i32_32x32x32_i8(e, b, acc[d], 0, 0, 0);
      }
    }

    // exact digit fold -> one f32 rounding (identical numerics to phase_l3)
    float dv[16];
#pragma unroll
    for (int r = 0; r < 16; ++r) {
      int slo = acc[0][r] + (acc[1][r] << 8);
      int shi = acc[2][r] + (acc[3][r] << 8);
      double ss = fma((double)shi, 65536.0, (double)slo);
      dv[r] = (float)(ss * 0x1p-32);
    }

    // ---- in-register v3 scan, exact t order tb..tb+31 (phase_v3 numerics)
    // phase 1: lo lanes advance t = tb+r
#pragma unroll
    for (int r = 0; r < 16; ++r) {
      float i3 = __fadd_rn(dv[r], b3r);
      float u  = __fadd_rn(v3, i3);
      bool s3  = (u >= 1.0f);
      float uv = s3 ? (u - 1.0f) : u;
      float av = __fadd_rn(ac, s3 ? 1.0f : 0.0f);
      if (!half) { v3 = uv; ac = av; }
    }
    v3 = __shfl_xor(v3, 32); ac = __shfl_xor(ac, 32);
    // phase 2: hi lanes advance t = tb+16+r
#pragma unroll
    for (int r = 0; r < 16; ++r) {
      float i3 = __fadd_rn(dv[r], b3r);
      float u  = __fadd_rn(v3, i3);
      bool s3  = (u >= 1.0f);
      float uv = s3 ? (u - 1.0f) : u;
      float av = __fadd_rn(ac, s3 ? 1.0f : 0.0f);
      if (half) { v3 = uv; ac = av; }
    }
    v3 = __shfl_xor(v3, 32); ac = __shfl_xor(ac, 32);
  }

  if (!half && l31 < CC)
    out[row * CC + l31] = ac * (1.0f / TT);
}

extern "C" void kernel_launch(void* const* d_in, const int* in_sizes, int n_in,
                              void* d_out, int out_size, void* d_ws, size_t ws_size,
                              hipStream_t stream)
{
  (void)in_sizes; (void)n_in; (void)out_size; (void)ws_size;
  const float* x  = (const float*)d_in[0];
  const float* W1 = (const float*)d_in[1];
  const float* b1 = (const float*)d_in[2];
  const float* W2 = (const float*)d_in[3];
  const float* b2 = (const float*)d_in[4];
  const float* W3 = (const float*)d_in[5];
  const float* b3 = (const float*)d_in[6];
  // d_in[7] = repeat (structurally 1 for this problem shape)
  float* out = (float*)d_out;
  char*  ws  = (char*)d_ws;

  signed char* dig    = (signed char*)(ws + WS_DIG);
  signed char* w3dig  = (signed char*)(ws + WS_W3D);
  ull*         masks  = (ull*)(ws + WS_MASK);
  unsigned*    masks2 = (unsigned*)(ws + WS_MASK2);

  prep_weights<<<2176, 256, 0, stream>>>(W2, W3, dig, w3dig);
  phase_s1<<<1024, 256, 0, stream>>>(x, W1, b1, masks);
  phase_gemmscan<<<256, 512, 0, stream>>>(dig, masks, b2, masks2);
  phase_l3v3<<<256, 256, 0, stream>>>(w3dig, masks2, b3, out);
}

// Round 13
// 170.055 us; speedup vs baseline: 2.0952x; 1.0068x over previous
//
#include <hip/hip_runtime.h>
#include <cmath>

#define BB  1024
#define TT  128
#define HH1 512
#define HH2 256
#define CC  18

// d_ws layout (byte offsets)
#define WS_DIG   0ull             // W2 digits: 8x4x16x2x32x16 i8 = 512 KB
#define WS_W3D   524288ull        // W3 digits LDS image: 32 KB
#define WS_MASK  557056ull        // s1 masks[row][chunk4][word8][t32] ull = 8 MB
#define WS_MASK2 8945664ull       // s2 masks[row][t][stripe8] u32 = 4 MB

typedef int  v4i  __attribute__((ext_vector_type(4)));
typedef int  v16i __attribute__((ext_vector_type(16)));
typedef unsigned long long ull;

__device__ __forceinline__ v4i expand_bits(unsigned bits) {
  v4i a;
  a.x = (int)((( bits        & 15u) * 0x204081u) & 0x01010101u);
  a.y = (int)((((bits >>  4) & 15u) * 0x204081u) & 0x01010101u);
  a.z = (int)((((bits >>  8) & 15u) * 0x204081u) & 0x01010101u);
  a.w = (int)((((bits >> 12) & 15u) * 0x204081u) & 0x01010101u);
  return a;
}

// ---- merged weight prep: W2 digits (bid<2048) | W3 digits (bid>=2048).
__global__ __launch_bounds__(256) void prep_weights(const float* __restrict__ W2,
    const float* __restrict__ W3, signed char* __restrict__ dig,
    signed char* __restrict__ w3dig)
{
  const int bid = blockIdx.x, tid = threadIdx.x;
  if (bid < 2048) {
    int i = bid * 256 + tid;                      // [0, 524288)
    int j = i & 15, n = (i >> 4) & 31, h = (i >> 9) & 1;
    int s = (i >> 10) & 15, d = (i >> 14) & 3, st = i >> 16;
    int h1 = s * 32 + h * 16 + j;
    int h2 = st * 32 + n;
    float w = W2[h2 * HH1 + h1];
    long long ll = llrint((double)w * 4294967296.0);
    int v = (int)ll;
    signed char d0 = (signed char)(v & 255); v = (v - d0) >> 8;
    signed char d1 = (signed char)(v & 255); v = (v - d1) >> 8;
    signed char d2 = (signed char)(v & 255); v = (v - d2) >> 8;
    signed char d3 = (signed char)v;
    dig[i] = (d == 0) ? d0 : (d == 1) ? d1 : (d == 2) ? d2 : d3;
  } else {
    int i = (bid - 2048) * 256 + tid;             // [0, 32768)
    int j = i & 15, col = (i >> 4) & 31, h = (i >> 9) & 1;
    int c8 = (i >> 10) & 7, d = (i >> 13) & 3;
    int h2 = c8 * 32 + h * 16 + j;
    float w = (col < CC) ? W3[col * HH2 + h2] : 0.0f;
    long long ll = llrint((double)w * 4294967296.0);
    int v = (int)ll;
    signed char d0 = (signed char)(v & 255); v = (v - d0) >> 8;
    signed char d1 = (signed char)(v & 255); v = (v - d1) >> 8;
    signed char d2 = (signed char)(v & 255); v = (v - d2) >> 8;
    signed char d3 = (signed char)v;
    w3dig[i] = (d == 0) ? d0 : (d == 1) ? d1 : (d == 2) ? d2 : d3;
  }
}

// ---- phase A: bit-exact layer-1 spike masks for all (row,t). One block/row.
// masks layout: [row][chunk(4)][word(8)][t32]
__global__ __launch_bounds__(256) void phase_s1(const float* __restrict__ x,
    const float* __restrict__ W1, const float* __restrict__ b1,
    ull* __restrict__ masks)
{
  __shared__ float xrow[TT];
  int row = blockIdx.x, tid = threadIdx.x, wv = tid >> 6, lane = tid & 63;
  for (int i = tid; i < TT; i += 256) xrow[i] = x[row * TT + i];
  const float w1a = W1[tid], w1b = W1[tid + 256];
  const float b1a = b1[tid], b1b = b1[tid + 256];
  float v1a = 0.f, v1b = 0.f;
  __syncthreads();
  for (int t = 0; t < TT; ++t) {
    float xt = xrow[t];
    float iA = __fadd_rn(__fmul_rn(xt, w1a), b1a);
    v1a = __fadd_rn(v1a, iA);
    bool sA = (v1a >= 1.0f);  v1a = sA ? (v1a - 1.0f) : v1a;
    float iB = __fadd_rn(__fmul_rn(xt, w1b), b1b);
    v1b = __fadd_rn(v1b, iB);
    bool sB = (v1b >= 1.0f);  v1b = sB ? (v1b - 1.0f) : v1b;
    ull mA = __ballot(sA);
    ull mB = __ballot(sB);
    if (lane == 0) {
      ull* p = masks + (size_t)row * 1024 + (size_t)(t >> 5) * 256 + (t & 31);
      p[(size_t)wv * 32]       = mA;              // word wv    : h1 [64wv, +64)
      p[(size_t)(4 + wv) * 32] = mB;              // word 4+wv  : h1 [256+64wv, +64)
    }
  }
}

// ---- fused layer 2, t-as-M-dimension (R10 compute, verified 65.5-68.9 us).
// R13: SIMD-pair TURNSTILE. Partner waves wv and wv+4 (same SIMD, wv&3)
// strictly alternate s-loop entry via an LDS counter: wave g spins until
// turn&1==g, runs the MFMA s-loop, increments, then does fold+scan while the
// partner s-loops. Mutual exclusion of s-loops forces the anti-phase schedule
// (one wave's MFMA burst covers the other's VALU burst) that the R5 sleep
// stagger failed to sustain. The turnstile orders NO data (all data deps are
// intra-wave) and the spin is bounded -> correctness is unconditional; worst
// case it degenerates to the un-forced schedule.
// LDS = 64 KB Bl + 16 KB mbuf + turnstile = 80 KB+. P/Q pairing load-bearing.
#define SPIN_LIMIT 20000
__global__ __launch_bounds__(512, 2) void phase_gemmscan(
    const signed char* __restrict__ Bd, const ull* __restrict__ masks,
    const float* __restrict__ b2, unsigned* __restrict__ masks2)
{
  __shared__ __align__(16) signed char Bl[65536];
  __shared__ __align__(16) ull mbuf[16][128];      // [pair][t] = 16 KB
  __shared__ int turn4[4];                         // per-SIMD turnstile

  const int bid = blockIdx.x;
  const int rowgrp = bid & 31, stripe = bid >> 5; // same-rowgrp -> same XCD
  const int tid = threadIdx.x, lane = tid & 63, wv = tid >> 6;
  const int half = lane >> 5, l31 = lane & 31;
  const int pairid = wv & 3, myg = wv >> 2;       // SIMD id, group 0/1

  if (tid < 4) turn4[tid] = 0;

  {
    const uint4* src = (const uint4*)(Bd + (size_t)stripe * 65536);
    uint4* dst = (uint4*)Bl;
#pragma unroll
    for (int i = 0; i < 8; ++i) dst[tid + 512 * i] = src[tid + 512 * i];
  }

  const signed char* bbase = Bl + half * 512 + l31 * 16;
  const float b2r = b2[stripe * 32 + l31];
  const unsigned hsh = half * 16;

  // A-row i = l31 -> t_local. tile1: lo-half regs get t 0..15 in order.
  const int tp1 = (l31 & 3) + ((l31 >> 3) << 2) + ((l31 & 4) ? 16 : 0);
  const int tp2 = tp1 ^ 16;                       // tile2: inverted halves

  __syncthreads();                                // Bl + turn4 ready

  for (int tau = 0; tau < 2; ++tau) {
    const int pr = wv + 8 * tau;                  // pair 0..15
    const int r1 = rowgrp * 32 + 2 * pr;
    const ull* mb1 = masks + (size_t)r1 * 1024;
    const ull* mb2 = mb1 + 1024;                  // row r1+1
    float v2 = 0.f;                               // lo: r1 state, hi: r2 state

    ull wP[8], wQ[8], wPn[8], wQn[8];
#pragma unroll
    for (int k = 0; k < 8; ++k) {
      wP[k] = mb1[k * 32 + tp1];
      wQ[k] = mb2[k * 32 + tp2];
    }

#pragma unroll
    for (int c = 0; c < 4; ++c) {
      if (c < 3) {                                // prefetch next chunk's masks
#pragma unroll
        for (int k = 0; k < 8; ++k) {
          wPn[k] = mb1[(c + 1) * 256 + k * 32 + tp1];
          wQn[k] = mb2[(c + 1) * 256 + k * 32 + tp2];
        }
      }

      v16i aP[4], aQ[4];
#pragma unroll
      for (int d = 0; d < 4; ++d) {
        aP[d] = (v16i){0,0,0,0,0,0,0,0,0,0,0,0,0,0,0,0};
        aQ[d] = (v16i){0,0,0,0,0,0,0,0,0,0,0,0,0,0,0,0};
      }

      // ---- turnstile wait: my turn to own the MFMA pipe (bounded spin)
      {
        int sp = 0;
        while (((__hip_atomic_load(&turn4[pairid], __ATOMIC_RELAXED,
                  __HIP_MEMORY_SCOPE_WORKGROUP) & 1) != myg) && sp < SPIN_LIMIT) {
          __builtin_amdgcn_s_sleep(1);
          ++sp;
        }
      }
      __builtin_amdgcn_sched_barrier(0);

      __builtin_amdgcn_s_setprio(1);
#pragma unroll
      for (int s = 0; s < 16; ++s) {
        v4i q0 = *(const v4i*)(bbase + (0 * 16 + s) * 1024);
        v4i q1 = *(const v4i*)(bbase + (1 * 16 + s) * 1024);
        v4i q2 = *(const v4i*)(bbase + (2 * 16 + s) * 1024);
        v4i q3 = *(const v4i*)(bbase + (3 * 16 + s) * 1024);
        unsigned shift = ((s & 1) << 5) + hsh;
        v4i eP = expand_bits((unsigned)(wP[s >> 1] >> shift) & 0xFFFFu);
        v4i eQ = expand_bits((unsigned)(wQ[s >> 1] >> shift) & 0xFFFFu);
        aP[0] = __builtin_amdgcn_mfma_i32_32x32x32_i8(eP, q0, aP[0], 0, 0, 0);
        aQ[0] = __builtin_amdgcn_mfma_i32_32x32x32_i8(eQ, q0, aQ[0], 0, 0, 0);
        aP[1] = __builtin_amdgcn_mfma_i32_32x32x32_i8(eP, q1, aP[1], 0, 0, 0);
        aQ[1] = __builtin_amdgcn_mfma_i32_32x32x32_i8(eQ, q1, aQ[1], 0, 0, 0);
        aP[2] = __builtin_amdgcn_mfma_i32_32x32x32_i8(eP, q2, aP[2], 0, 0, 0);
        aQ[2] = __builtin_amdgcn_mfma_i32_32x32x32_i8(eQ, q2, aQ[2], 0, 0, 0);
        aP[3] = __builtin_amdgcn_mfma_i32_32x32x32_i8(eP, q3, aP[3], 0, 0, 0);
        aQ[3] = __builtin_amdgcn_mfma_i32_32x32x32_i8(eQ, q3, aQ[3], 0, 0, 0);
      }
      __builtin_amdgcn_s_setprio(0);
      __builtin_amdgcn_sched_barrier(0);

      // ---- turnstile pass: partner may enter its s-loop now
      if (lane == 0)
        __hip_atomic_fetch_add(&turn4[pairid], 1, __ATOMIC_RELAXED,
                               __HIP_MEMORY_SCOPE_WORKGROUP);
      __builtin_amdgcn_sched_barrier(0);

      // exact digit fold -> one f32 rounding (bit-identical).
      // dP[r]: tile1 value at t_local = r + 16*half; dQ[r]: r + 16*(1-half).
      float dP[16], dQ[16];
#pragma unroll
      for (int r = 0; r < 16; ++r) {
        int sloP = aP[0][r] + (aP[1][r] << 8);
        int shiP = aP[2][r] + (aP[3][r] << 8);
        double ssP = fma((double)shiP, 65536.0, (double)sloP);  // exact
        dP[r] = (float)(ssP * 0x1p-32);                         // one rounding
        int sloQ = aQ[0][r] + (aQ[1][r] << 8);
        int shiQ = aQ[2][r] + (aQ[3][r] << 8);
        double ssQ = fma((double)shiQ, 65536.0, (double)sloQ);
        dQ[r] = (float)(ssQ * 0x1p-32);
      }

      // ---- in-register v2 scan of 32 t (exact order t = tb..tb+31)
      const int tb = c * 32;
      // phase 1: lo lanes scan r1 (dP), hi lanes scan r2 (dQ); t = tb + r
#pragma unroll
      for (int r = 0; r < 16; ++r) {
        float val = half ? dQ[r] : dP[r];
        float i2 = __fadd_rn(val, b2r);
        v2 = __fadd_rn(v2, i2);
        bool s2 = (v2 >= 1.0f);  v2 = s2 ? (v2 - 1.0f) : v2;
        ull m = __ballot(s2);                     // lo32: r1 word, hi32: r2
        if (lane == 0) mbuf[pr][tb + r] = m;
      }
      v2 = __shfl_xor(v2, 32);                    // exchange row states
      // phase 2: lo lanes scan r2 (dQ), hi lanes scan r1 (dP); t = tb+16+r
#pragma unroll
      for (int r = 0; r < 16; ++r) {
        float val = half ? dP[r] : dQ[r];
        float i2 = __fadd_rn(val, b2r);
        v2 = __fadd_rn(v2, i2);
        bool s2 = (v2 >= 1.0f);  v2 = s2 ? (v2 - 1.0f) : v2;
        ull m = __ballot(s2);                     // lo32: r2 word, hi32: r1
        if (lane == 0) mbuf[pr][tb + 16 + r] = (m >> 32) | (m << 32);
      }
      v2 = __shfl_xor(v2, 32);                    // restore arrangement

      if (c < 3) {
#pragma unroll
        for (int k = 0; k < 8; ++k) { wP[k] = wPn[k]; wQ[k] = wQn[k]; }
      }
    }
  }

  // ---- batch flush: mbuf -> masks2[row][t][stripe8] (fire-and-forget)
  __syncthreads();
  {
    const ull* mb = &mbuf[0][0];
    unsigned* base = masks2 + (size_t)rowgrp * 32 * 1024 + stripe;
#pragma unroll
    for (int i = 0; i < 4; ++i) {
      int e = i * 512 + tid;                      // [0, 2048)
      int p = e >> 7, t = e & 127;                // pair, timestep
      ull m = mb[e];
      unsigned* q = base + (size_t)(2 * p) * 1024 + t * 8;
      q[0]    = (unsigned)m;                      // row rowgrp*32+2p
      q[1024] = (unsigned)(m >> 32);              // row rowgrp*32+2p+1
    }
  }
}

// ---- fused layer 3 + v3 scan (R10): t-as-M, in-register v3, no D3 buffer.
// Block = 256 thr (4 waves); wave owns ONE batch row (row = bid*4+wv), all
// 128 t. masks2 is [row][t][stripe8]: each lane reads its 8 K-words as two
// dwordx4 (32 B contiguous); a wave covers a 1 KB contiguous span per chunk.
__global__ __launch_bounds__(256) void phase_l3v3(const signed char* __restrict__ W3d,
    const unsigned* __restrict__ masks2, const float* __restrict__ b3,
    float* __restrict__ out)
{
  __shared__ __align__(16) signed char Bl[32768];
  const int bid = blockIdx.x;
  const int tid = threadIdx.x, lane = tid & 63, wv = tid >> 6;
  const int half = lane >> 5, l31 = lane & 31;

  {
    const uint4* src = (const uint4*)W3d;
    uint4* dst = (uint4*)Bl;
#pragma unroll
    for (int i = 0; i < 8; ++i) dst[tid + 256 * i] = src[tid + 256 * i];
  }

  const int row = bid * 4 + wv;
  const unsigned* mrow = masks2 + (size_t)row * (TT * 8);
  const signed char* bbase = Bl + half * 512 + l31 * 16;
  const float b3r = b3[l31 < CC ? l31 : 0];
  const unsigned hsh = half * 16;
  // A-row l31 -> t_local (same permutation as gemmscan; fold reg r = tb+r+16*half)
  const int tp1 = (l31 & 3) + ((l31 >> 3) << 2) + ((l31 & 4) ? 16 : 0);

  __syncthreads();

  float v3 = 0.f, ac = 0.f;                       // canonical state in lo lanes

  for (int c = 0; c < 4; ++c) {
    unsigned w8[8];
    {
      const unsigned* mp = mrow + (size_t)(c * 32 + tp1) * 8;
      *(uint4*)&w8[0] = *(const uint4*)mp;
      *(uint4*)&w8[4] = *(const uint4*)(mp + 4);
    }

    v16i acc[4];
#pragma unroll
    for (int d = 0; d < 4; ++d)
      acc[d] = (v16i){0,0,0,0,0,0,0,0,0,0,0,0,0,0,0,0};

#pragma unroll
    for (int c8 = 0; c8 < 8; ++c8) {
      v4i e = expand_bits((w8[c8] >> hsh) & 0xFFFFu);
#pragma unroll
      for (int d = 0; d < 4; ++d) {
        v4i b = *(const v4i*)(bbase + (d * 8 + c8) * 1024);
        acc[d] = __builtin_amdgcn_mfma_i32_32x32x32_i8(e, b, acc[d], 0, 0, 0);
      }
    }

    // exact digit fold -> one f32 rounding (identical numerics to phase_l3)
    float dv[16];
#pragma unroll
    for (int r = 0; r < 16; ++r) {
      int slo = acc[0][r] + (acc[1][r] << 8);
      int shi = acc[2][r] + (acc[3][r] << 8);
      double ss = fma((double)shi, 65536.0, (double)slo);
      dv[r] = (float)(ss * 0x1p-32);
    }

    // ---- in-register v3 scan, exact t order tb..tb+31 (phase_v3 numerics)
    // phase 1: lo lanes advance t = tb+r
#pragma unroll
    for (int r = 0; r < 16; ++r) {
      float i3 = __fadd_rn(dv[r], b3r);
      float u  = __fadd_rn(v3, i3);
      bool s3  = (u >= 1.0f);
      float uv = s3 ? (u - 1.0f) : u;
      float av = __fadd_rn(ac, s3 ? 1.0f : 0.0f);
      if (!half) { v3 = uv; ac = av; }
    }
    v3 = __shfl_xor(v3, 32); ac = __shfl_xor(ac, 32);
    // phase 2: hi lanes advance t = tb+16+r
#pragma unroll
    for (int r = 0; r < 16; ++r) {
      float i3 = __fadd_rn(dv[r], b3r);
      float u  = __fadd_rn(v3, i3);
      bool s3  = (u >= 1.0f);
      float uv = s3 ? (u - 1.0f) : u;
      float av = __fadd_rn(ac, s3 ? 1.0f : 0.0f);
      if (half) { v3 = uv; ac = av; }
    }
    v3 = __shfl_xor(v3, 32); ac = __shfl_xor(ac, 32);
  }

  if (!half && l31 < CC)
    out[row * CC + l31] = ac * (1.0f / TT);
}

extern "C" void kernel_launch(void* const* d_in, const int* in_sizes, int n_in,
                              void* d_out, int out_size, void* d_ws, size_t ws_size,
                              hipStream_t stream)
{
  (void)in_sizes; (void)n_in; (void)out_size; (void)ws_size;
  const float* x  = (const float*)d_in[0];
  const float* W1 = (const float*)d_in[1];
  const float* b1 = (const float*)d_in[2];
  const float* W2 = (const float*)d_in[3];
  const float* b2 = (const float*)d_in[4];
  const float* W3 = (const float*)d_in[5];
  const float* b3 = (const float*)d_in[6];
  // d_in[7] = repeat (structurally 1 for this problem shape)
  float* out = (float*)d_out;
  char*  ws  = (char*)d_ws;

  signed char* dig    = (signed char*)(ws + WS_DIG);
  signed char* w3dig  = (signed char*)(ws + WS_W3D);
  ull*         masks  = (ull*)(ws + WS_MASK);
  unsigned*    masks2 = (unsigned*)(ws + WS_MASK2);

  prep_weights<<<2176, 256, 0, stream>>>(W2, W3, dig, w3dig);
  phase_s1<<<1024, 256, 0, stream>>>(x, W1, b1, masks);
  phase_gemmscan<<<256, 512, 0, stream>>>(dig, masks, b2, masks2);
  phase_l3v3<<<256, 256, 0, stream>>>(w3dig, masks2, b3, out);
}